// Round 2
// baseline (393.189 us; speedup 1.0000x reference)
//
#include <hip/hip_runtime.h>

typedef __attribute__((ext_vector_type(8))) short short8;
typedef __attribute__((ext_vector_type(8))) unsigned short us8;
typedef __attribute__((ext_vector_type(4))) unsigned short us4;
typedef __attribute__((ext_vector_type(4))) float f32x4;

__device__ __forceinline__ float bf2f(unsigned short h) {
  return __uint_as_float(((unsigned int)h) << 16);
}
__device__ __forceinline__ unsigned short f2bf(float f) {
  unsigned int u = __float_as_uint(f);
  u += 0x7FFF + ((u >> 16) & 1);
  return (unsigned short)(u >> 16);
}

// async global->LDS, 16B per lane. LDS dest is wave-uniform base + lane*16.
__device__ __forceinline__ void gload16(const void* g, void* l) {
  __builtin_amdgcn_global_load_lds(
      (const __attribute__((address_space(1))) unsigned int*)g,
      (__attribute__((address_space(3))) unsigned int*)l, 16, 0, 0);
}

#define BM 128
#define BN 128
#define BK 32

struct EpiParams {
  const float* bias;   // [out cols] or null
  const float* aux0;   // EPI3: query_feat (residual)
  const float* aux1;
  long  saux;
  float scale;
};

// C[r][c] = sum_k A[r][k] * B[c][k]   (B^T input form; A,B bf16 row-major, K contiguous)
template<int EPI>
__global__ __launch_bounds__(256)
void gemm_bt(const unsigned short* __restrict__ A, const unsigned short* __restrict__ B,
             void* __restrict__ Cout, int Kd, int lda, int ldb, int ldc,
             long sA, long sB, long sC, EpiParams ep)
{
  __shared__ __attribute__((aligned(16))) char smem[16384];
  char* Al = smem;
  char* Bl = smem + 8192;

  const int t    = threadIdx.x;
  const int lane = t & 63;
  const int wid  = t >> 6;
  const int wr   = wid >> 1;
  const int wc   = wid & 1;
  const int tr   = lane & 15;
  const int tg   = lane >> 4;

  const int bz    = blockIdx.z;
  const int rbase = blockIdx.y * BM;
  const int cbase = blockIdx.x * BN;

  const unsigned short* Ab = A + (long)bz * sA;
  const unsigned short* Bb = B + (long)bz * sB;
  const char* Asrc = (const char*)(Ab + (long)rbase * lda);
  const char* Bsrc = (const char*)(Bb + (long)cbase * ldb);
  const long lda_b = (long)lda * 2;
  const long ldb_b = (long)ldb * 2;

  f32x4 acc[4][4] = {};

  for (int k0 = 0; k0 < Kd; k0 += BK) {
#pragma unroll
    for (int it = 0; it < 2; ++it) {
      const int boff = (it * 4 + wid) * 1024 + lane * 16;
      const int r  = boff >> 6;
      const int cb = boff & 63;
      gload16(Asrc + (long)r * lda_b + (k0 * 2 + cb), Al + (it * 4 + wid) * 1024);
      gload16(Bsrc + (long)r * ldb_b + (k0 * 2 + cb), Bl + (it * 4 + wid) * 1024);
    }
    __syncthreads();

    short8 af[4], bf[4];
#pragma unroll
    for (int m = 0; m < 4; ++m)
      af[m] = *(const short8*)(Al + ((wr * 64 + m * 16 + tr) * 32 + tg * 8) * 2);
#pragma unroll
    for (int n = 0; n < 4; ++n)
      bf[n] = *(const short8*)(Bl + ((wc * 64 + n * 16 + tr) * 32 + tg * 8) * 2);
#pragma unroll
    for (int m = 0; m < 4; ++m)
#pragma unroll
      for (int n = 0; n < 4; ++n)
        acc[m][n] = __builtin_amdgcn_mfma_f32_16x16x32_bf16(af[m], bf[n], acc[m][n], 0, 0, 0);
    __syncthreads();
  }

  if (EPI == 0) {  // bf16 out (+optional bias): Q, K projections
    unsigned short* C = (unsigned short*)Cout + (long)bz * sC;
#pragma unroll
    for (int n = 0; n < 4; ++n) {
      const int col = cbase + wc * 64 + n * 16 + tr;
      const float bv = ep.bias ? ep.bias[col] : 0.f;
#pragma unroll
      for (int m = 0; m < 4; ++m) {
#pragma unroll
        for (int i = 0; i < 4; ++i) {
          const int row = rbase + wr * 64 + m * 16 + tg * 4 + i;
          C[(long)row * ldc + col] = f2bf(acc[m][n][i] + bv);
        }
      }
    }
  } else if (EPI == 1) {  // V-projection writing V^T: Vt[b][e][m]
    unsigned short* C = (unsigned short*)Cout;
#pragma unroll
    for (int n = 0; n < 4; ++n) {
      const int col = cbase + wc * 64 + n * 16 + tr;
      const float bv = ep.bias ? ep.bias[col] : 0.f;
#pragma unroll
      for (int m = 0; m < 4; ++m) {
        const int row0 = rbase + wr * 64 + m * 16 + tg * 4;
        const int b  = row0 >> 11;
        const int ml = row0 & 2047;
        us4 v;
#pragma unroll
        for (int i = 0; i < 4; ++i) v[i] = f2bf(acc[m][n][i] + bv);
        *(us4*)(C + ((long)b * 512 + col) * 2048 + ml) = v;
      }
    }
  } else {  // EPI 3: fp32 out = acc + bias + residual(query_feat)
    float* C = (float*)Cout;
    const float* qf = ep.aux0;
#pragma unroll
    for (int n = 0; n < 4; ++n) {
      const int col = cbase + wc * 64 + n * 16 + tr;
      const float bv = ep.bias ? ep.bias[col] : 0.f;
#pragma unroll
      for (int m = 0; m < 4; ++m) {
#pragma unroll
        for (int i = 0; i < 4; ++i) {
          const int row = rbase + wr * 64 + m * 16 + tg * 4 + i;
          C[(long)row * 512 + col] = acc[m][n][i] + bv + qf[(long)row * 512 + col];
        }
      }
    }
  }
}

// ---------------- fused flash attention with distance bias ----------------
// grid (8 batches, 32 q-blocks), 512 threads. Q-block = 64 rows.
// LDS: K tile [64][512], V^T tile [512][64], P [64][64], all XOR-swizzled.
// Per wave w: QK rows (w&3)*16, cols (w>>2)*32 (2 n-frags); PV owns O cols w*64.
__global__ __launch_bounds__(512, 2)
void fused_attn(const unsigned short* Qg, const unsigned short* __restrict__ Kg,
                const unsigned short* __restrict__ VTg,
                const float* __restrict__ qxyzg, const float* __restrict__ kxyzg,
                unsigned short* ATT)
{
  __shared__ __attribute__((aligned(16))) unsigned short sK[64 * 512];   // 64 KB
  __shared__ __attribute__((aligned(16))) unsigned short sVT[512 * 64];  // 64 KB
  __shared__ __attribute__((aligned(16))) unsigned short sP[64 * 64];    // 8 KB
  __shared__ __attribute__((aligned(16))) float sPmax[2][64];
  __shared__ __attribute__((aligned(16))) float sPsum[2][64];
  __shared__ __attribute__((aligned(16))) float sMnew[64];
  __shared__ __attribute__((aligned(16))) float sScale[64];

  const int b  = blockIdx.x;          // linear wgid % 8 -> XCD-aligned per batch
  const int q0 = blockIdx.y * 64;
  const int tid  = threadIdx.x;
  const int lane = tid & 63;
  const int w    = tid >> 6;
  const int tr   = lane & 15;
  const int tg   = lane >> 4;
  const int mq   = w & 3;    // QK row block (16 rows)
  const int cg   = w >> 1 >> 1; // QK col group (0/1), 32 cols

  const float SCALE = 0.044194173824159216f;  // 1/sqrt(512)

  // Q fragments in registers: rows q0 + mq*16 + tr, all 512 K
  const unsigned short* Qrow = Qg + ((long)b * 2048 + q0 + mq * 16 + tr) * 512;
  short8 qf[16];
#pragma unroll
  for (int c = 0; c < 16; ++c) qf[c] = *(const short8*)(Qrow + c * 32 + tg * 8);

  // qxyz for this lane's 4 S-rows
  float qx[4], qy[4], qz[4];
#pragma unroll
  for (int i = 0; i < 4; ++i) {
    const float* p = qxyzg + ((long)b * 2048 + q0 + mq * 16 + tg * 4 + i) * 3;
    qx[i] = p[0]; qy[i] = p[1]; qz[i] = p[2];
  }

  f32x4 om[4][4] = {};               // O accumulator: rows 64, cols w*64..+64
  float m_run = -1e30f, l_run = 0.f; // per-row state (wave0, lane=row)

  // prologue: stage K tile 0
#pragma unroll
  for (int j = 0; j < 8; ++j) {
    const int r = w * 8 + j;
    gload16(Kg + ((long)b * 2048 + r) * 512 + ((lane ^ (r & 7)) * 8), sK + r * 512);
  }

#pragma unroll 1
  for (int t = 0; t < 32; ++t) {
    const int kv0 = t * 64;
    asm volatile("s_waitcnt vmcnt(0)" ::: "memory");  // K(t) landed
    __builtin_amdgcn_s_barrier();
    asm volatile("" ::: "memory");

    // stage V^T(t): rows j*64+w*8..+8 per iter, pre-swizzled source
#pragma unroll
    for (int j = 0; j < 8; ++j) {
      const int eb = j * 64 + w * 8;
      const int e  = eb + (lane >> 3);
      const int sl = lane & 7;
      gload16(VTg + ((long)b * 512 + e) * 2048 + kv0 + ((sl ^ (e & 7)) * 8), sVT + eb * 64);
    }

    // kxyz for this lane's 2 S-cols
    float kx[2], ky[2], kz[2];
#pragma unroll
    for (int n = 0; n < 2; ++n) {
      const float* p = kxyzg + ((long)b * 2048 + kv0 + cg * 32 + n * 16 + tr) * 3;
      kx[n] = p[0]; ky[n] = p[1]; kz[n] = p[2];
    }

    // QK^T: S[16 rows][2x16 cols], contraction over 512
    f32x4 sa[2];
    sa[0] = f32x4{0.f, 0.f, 0.f, 0.f};
    sa[1] = f32x4{0.f, 0.f, 0.f, 0.f};
#pragma unroll
    for (int ks = 0; ks < 16; ++ks) {
#pragma unroll
      for (int n = 0; n < 2; ++n) {
        const int r = cg * 32 + n * 16 + tr;  // K row = S col
        const short8 bfr = *(const short8*)((const char*)sK + r * 1024 +
                             (((ks * 32 + tg * 8) * 2) ^ ((r & 7) << 4)));
        sa[n] = __builtin_amdgcn_mfma_f32_16x16x32_bf16(qf[ks], bfr, sa[n], 0, 0, 0);
      }
    }

    // scale + distance bias + per-row (16-col-group) max
    f32x4 pm;
#pragma unroll
    for (int i = 0; i < 4; ++i) {
      float best = -1e30f;
#pragma unroll
      for (int n = 0; n < 2; ++n) {
        const float dx = qx[i] - kx[n], dy = qy[i] - ky[n], dz = qz[i] - kz[n];
        const float dd = sqrtf(fmaxf(dx * dx + dy * dy + dz * dz, 1e-12f));
        const float v  = sa[n][i] * SCALE + fmaxf(-2.f * dd, -18.420680743952367f);
        sa[n][i] = v;
        best = fmaxf(best, v);
      }
      pm[i] = best;
    }
#pragma unroll
    for (int off = 1; off <= 8; off <<= 1)
#pragma unroll
      for (int i = 0; i < 4; ++i) pm[i] = fmaxf(pm[i], __shfl_xor(pm[i], off, 64));
    if (tr == 0) *(f32x4*)&sPmax[cg][mq * 16 + tg * 4] = pm;

    asm volatile("s_waitcnt lgkmcnt(0)" ::: "memory");
    __builtin_amdgcn_s_barrier();                       // B_a
    asm volatile("" ::: "memory");

    // prefetch K(t+1) while softmax runs (readers of K(t) all done at B_a)
    if (t + 1 < 32) {
#pragma unroll
      for (int j = 0; j < 8; ++j) {
        const int r = w * 8 + j;
        gload16(Kg + ((long)b * 2048 + kv0 + 64 + r) * 512 + ((lane ^ (r & 7)) * 8),
                sK + r * 512);
      }
    }

    if (w == 0) {  // per-row running state, lane = row
      const float tm = fmaxf(sPmax[0][lane], sPmax[1][lane]);
      const float mn = fmaxf(m_run, tm);
      const float sc = __expf(m_run - mn);
      m_run = mn; l_run *= sc;
      sMnew[lane] = mn; sScale[lane] = sc;
    }
    asm volatile("s_waitcnt lgkmcnt(0)" ::: "memory");
    __builtin_amdgcn_s_barrier();                       // B_b
    asm volatile("" ::: "memory");

    // P = exp(S - m_new) -> bf16 LDS (swizzled); partial row sums; O rescale
    f32x4 ps = {0.f, 0.f, 0.f, 0.f};
#pragma unroll
    for (int i = 0; i < 4; ++i) {
      const float mn = sMnew[mq * 16 + tg * 4 + i];
      const int r = mq * 16 + tg * 4 + i;
#pragma unroll
      for (int n = 0; n < 2; ++n) {
        const float p = __expf(sa[n][i] - mn);
        ps[i] += p;
        const int c = cg * 32 + n * 16 + tr;
        *(unsigned short*)((char*)sP + r * 128 + ((c * 2) ^ ((r & 7) << 4))) = f2bf(p);
      }
    }
#pragma unroll
    for (int off = 1; off <= 8; off <<= 1)
#pragma unroll
      for (int i = 0; i < 4; ++i) ps[i] += __shfl_xor(ps[i], off, 64);
    if (tr == 0) *(f32x4*)&sPsum[cg][mq * 16 + tg * 4] = ps;

#pragma unroll
    for (int mo = 0; mo < 4; ++mo) {
      const f32x4 sc4 = *(const f32x4*)&sScale[mo * 16 + tg * 4];
#pragma unroll
      for (int n = 0; n < 4; ++n)
#pragma unroll
        for (int i = 0; i < 4; ++i) om[mo][n][i] *= sc4[i];
    }

    asm volatile("s_waitcnt lgkmcnt(0)" ::: "memory");
    if (t + 1 < 32) asm volatile("s_waitcnt vmcnt(8)" ::: "memory");  // V(t) landed, K(t+1) in flight
    else            asm volatile("s_waitcnt vmcnt(0)" ::: "memory");
    __builtin_amdgcn_s_barrier();                       // B_c
    asm volatile("" ::: "memory");

    if (w == 0) l_run += sPsum[0][lane] + sPsum[1][lane];

    // PV: O[64][w*64..+64] += P[64][64] * V^T
#pragma unroll
    for (int ks2 = 0; ks2 < 2; ++ks2) {
      short8 pa[4];
#pragma unroll
      for (int mo = 0; mo < 4; ++mo) {
        const int r = mo * 16 + tr;
        pa[mo] = *(const short8*)((const char*)sP + r * 128 +
                   ((ks2 * 64 + tg * 16) ^ ((r & 7) << 4)));
      }
#pragma unroll
      for (int n = 0; n < 4; ++n) {
        const int e = w * 64 + n * 16 + tr;
        const short8 vb = *(const short8*)((const char*)sVT + e * 128 +
                            ((ks2 * 64 + tg * 16) ^ ((e & 7) << 4)));
#pragma unroll
        for (int mo = 0; mo < 4; ++mo)
          om[mo][n] = __builtin_amdgcn_mfma_f32_16x16x32_bf16(pa[mo], vb, om[mo][n], 0, 0, 0);
      }
    }
  }

  // finalize: divide by l, write ATT bf16
  if (w == 0) sScale[lane] = 1.f / l_run;
  asm volatile("s_waitcnt lgkmcnt(0)" ::: "memory");
  __builtin_amdgcn_s_barrier();
  asm volatile("" ::: "memory");
#pragma unroll
  for (int mo = 0; mo < 4; ++mo) {
    const f32x4 inv4 = *(const f32x4*)&sScale[mo * 16 + tg * 4];
#pragma unroll
    for (int n = 0; n < 4; ++n) {
      const int col = w * 64 + n * 16 + tr;
#pragma unroll
      for (int i = 0; i < 4; ++i) {
        const long row = (long)b * 2048 + q0 + mo * 16 + tg * 4 + i;
        ATT[row * 512 + col] = f2bf(om[mo][n][i] * inv4[i]);
      }
    }
  }
}

// LayerNorm rows of 512 fp32; one wave per row
__global__ __launch_bounds__(256)
void ln_rows(const float* __restrict__ X, const float* __restrict__ g,
             const float* __restrict__ b, float* __restrict__ O)
{
  const int row  = blockIdx.x * 4 + (threadIdx.x >> 6);
  const int lane = threadIdx.x & 63;
  const float* xp = X + (long)row * 512;

  f32x4 v0 = *(const f32x4*)(xp + lane * 4);
  f32x4 v1 = *(const f32x4*)(xp + 256 + lane * 4);

  float s = 0.f;
#pragma unroll
  for (int j = 0; j < 4; ++j) s += v0[j] + v1[j];
#pragma unroll
  for (int off = 32; off; off >>= 1) s += __shfl_xor(s, off, 64);
  const float mu = s * (1.f / 512.f);

  float vs = 0.f;
#pragma unroll
  for (int j = 0; j < 4; ++j) {
    float d0 = v0[j] - mu, d1 = v1[j] - mu;
    vs += d0 * d0 + d1 * d1;
  }
#pragma unroll
  for (int off = 32; off; off >>= 1) vs += __shfl_xor(vs, off, 64);
  const float r = rsqrtf(vs * (1.f / 512.f) + 1e-5f);

  f32x4 g0 = *(const f32x4*)(g + lane * 4);
  f32x4 g1 = *(const f32x4*)(g + 256 + lane * 4);
  f32x4 b0 = *(const f32x4*)(b + lane * 4);
  f32x4 b1 = *(const f32x4*)(b + 256 + lane * 4);

  f32x4 o0, o1;
#pragma unroll
  for (int j = 0; j < 4; ++j) {
    o0[j] = (v0[j] - mu) * r * g0[j] + b0[j];
    o1[j] = (v1[j] - mu) * r * g1[j] + b1[j];
  }
  float* op = O + (long)row * 512;
  *(f32x4*)(op + lane * 4) = o0;
  *(f32x4*)(op + 256 + lane * 4) = o1;
}

// fp32 -> bf16, 8 elements per thread
__global__ __launch_bounds__(256)
void cvt_bf16(const float* __restrict__ src, unsigned short* __restrict__ dst, int nvec)
{
  const int i = blockIdx.x * blockDim.x + threadIdx.x;
  if (i >= nvec) return;
  const f32x4* s = (const f32x4*)src;
  f32x4 a = s[(long)i * 2];
  f32x4 c = s[(long)i * 2 + 1];
  us8 o;
#pragma unroll
  for (int j = 0; j < 4; ++j) { o[j] = f2bf(a[j]); o[4 + j] = f2bf(c[j]); }
  *(us8*)(dst + (long)i * 8) = o;
}

extern "C" void kernel_launch(void* const* d_in, const int* in_sizes, int n_in,
                              void* d_out, int out_size, void* d_ws, size_t ws_size,
                              hipStream_t stream)
{
  const float* qxyz  = (const float*)d_in[0];
  const float* qfeat = (const float*)d_in[1];
  const float* kxyz  = (const float*)d_in[2];
  const float* kfeat = (const float*)d_in[3];
  const float* Wq = (const float*)d_in[4];
  const float* bq = (const float*)d_in[5];
  const float* Wk = (const float*)d_in[6];
  const float* bk = (const float*)d_in[7];
  const float* Wv = (const float*)d_in[8];
  const float* bv = (const float*)d_in[9];
  const float* Wo = (const float*)d_in[10];
  const float* bo = (const float*)d_in[11];
  const float* lng = (const float*)d_in[12];
  const float* lnb = (const float*)d_in[13];

  const long SZ_FEAT = 16777216;            // 8*2048*512*2
  char* ws = (char*)d_ws;
  if (ws_size < (size_t)85983232) return;   // ~86 MB used

  unsigned short* XQ  = (unsigned short*)(ws);
  unsigned short* XK  = (unsigned short*)(ws + SZ_FEAT);
  unsigned short* QB  = (unsigned short*)(ws + 2 * SZ_FEAT);
  unsigned short* KB  = (unsigned short*)(ws + 3 * SZ_FEAT);
  unsigned short* VT  = (unsigned short*)(ws + 4 * SZ_FEAT);
  unsigned short* WQB = (unsigned short*)(ws + 5 * SZ_FEAT);
  unsigned short* WKB = WQB + 262144;
  unsigned short* WVB = WQB + 524288;
  unsigned short* WOB = WQB + 786432;
  unsigned short* ATT = QB;                 // alias: per-block Q rows read before ATT rows written
  float* XRES = (float*)ws;                 // alias: XQ/XK dead after projections

  // 1. conversions
  cvt_bf16<<<4096, 256, 0, stream>>>(qfeat, XQ, 1048576);
  cvt_bf16<<<4096, 256, 0, stream>>>(kfeat, XK, 1048576);
  cvt_bf16<<<128, 256, 0, stream>>>(Wq, WQB, 32768);
  cvt_bf16<<<128, 256, 0, stream>>>(Wk, WKB, 32768);
  cvt_bf16<<<128, 256, 0, stream>>>(Wv, WVB, 32768);
  cvt_bf16<<<128, 256, 0, stream>>>(Wo, WOB, 32768);

  // 2. projections
  EpiParams e0{}; e0.bias = bq;
  gemm_bt<0><<<dim3(4, 128, 1), 256, 0, stream>>>(XQ, WQB, QB, 512, 512, 512, 512, 0, 0, 0, e0);
  EpiParams e1{}; e1.bias = bk;
  gemm_bt<0><<<dim3(4, 128, 1), 256, 0, stream>>>(XK, WKB, KB, 512, 512, 512, 512, 0, 0, 0, e1);
  EpiParams e2{}; e2.bias = bv;
  gemm_bt<1><<<dim3(4, 128, 1), 256, 0, stream>>>(XK, WVB, VT, 512, 512, 512, 0, 0, 0, 0, e2);

  // 3-5. fused scores + distance bias + softmax + PV
  fused_attn<<<dim3(8, 32), 512, 0, stream>>>(QB, KB, VT, qxyz, kxyz, ATT);

  // 6. out projection + bias + residual -> x (fp32)
  EpiParams eo{}; eo.bias = bo; eo.aux0 = qfeat;
  gemm_bt<3><<<dim3(4, 128, 1), 256, 0, stream>>>(ATT, WOB, XRES, 512, 512, 512, 512, 0, 0, 0, eo);

  // 7. LayerNorm -> out
  ln_rows<<<4096, 256, 0, stream>>>(XRES, lng, lnb, (float*)d_out);
}

// Round 3
// 279.475 us; speedup vs baseline: 1.4069x; 1.4069x over previous
//
#include <hip/hip_runtime.h>

typedef __attribute__((ext_vector_type(8))) short short8;
typedef __attribute__((ext_vector_type(8))) unsigned short us8;
typedef __attribute__((ext_vector_type(4))) unsigned short us4;
typedef __attribute__((ext_vector_type(4))) float f32x4;

__device__ __forceinline__ float bf2f(unsigned short h) {
  return __uint_as_float(((unsigned int)h) << 16);
}
__device__ __forceinline__ unsigned short f2bf(float f) {
  unsigned int u = __float_as_uint(f);
  u += 0x7FFF + ((u >> 16) & 1);
  return (unsigned short)(u >> 16);
}

// async global->LDS, 16B per lane. LDS dest is wave-uniform base + lane*16.
__device__ __forceinline__ void gload16(const void* g, void* l) {
  __builtin_amdgcn_global_load_lds(
      (const __attribute__((address_space(1))) unsigned int*)g,
      (__attribute__((address_space(3))) unsigned int*)l, 16, 0, 0);
}

#define BM 128
#define BN 128
#define BK 32

struct EpiParams {
  const float* bias;   // [out cols] or null
  const float* aux0;   // EPI2: query_xyz ; EPI3: query_feat (residual)
  const float* aux1;   // EPI2: key_xyz
  long  saux;          // xyz batch stride (elements)
  float scale;         // EPI2: 1/sqrt(D)
};

// ---------- small-tile GEMM (projections / out-proj), proven R1 structure ----------
// C[r][c] = sum_k A[r][k] * B[c][k]
template<int EPI>
__global__ __launch_bounds__(256)
void gemm_bt(const unsigned short* __restrict__ A, const unsigned short* __restrict__ B,
             void* __restrict__ Cout, int Kd, int lda, int ldb, int ldc,
             long sA, long sB, long sC, EpiParams ep)
{
  __shared__ __attribute__((aligned(16))) char smem[16384];
  char* Al = smem;
  char* Bl = smem + 8192;

  const int t    = threadIdx.x;
  const int lane = t & 63;
  const int wid  = t >> 6;
  const int wr   = wid >> 1;
  const int wc   = wid & 1;
  const int tr   = lane & 15;
  const int tg   = lane >> 4;

  const int bz    = blockIdx.z;
  const int rbase = blockIdx.y * BM;
  const int cbase = blockIdx.x * BN;

  const unsigned short* Ab = A + (long)bz * sA;
  const unsigned short* Bb = B + (long)bz * sB;
  const char* Asrc = (const char*)(Ab + (long)rbase * lda);
  const char* Bsrc = (const char*)(Bb + (long)cbase * ldb);
  const long lda_b = (long)lda * 2;
  const long ldb_b = (long)ldb * 2;

  f32x4 acc[4][4] = {};

  for (int k0 = 0; k0 < Kd; k0 += BK) {
#pragma unroll
    for (int it = 0; it < 2; ++it) {
      const int boff = (it * 4 + wid) * 1024 + lane * 16;
      const int r  = boff >> 6;
      const int cb = boff & 63;
      gload16(Asrc + (long)r * lda_b + (k0 * 2 + cb), Al + (it * 4 + wid) * 1024);
      gload16(Bsrc + (long)r * ldb_b + (k0 * 2 + cb), Bl + (it * 4 + wid) * 1024);
    }
    __syncthreads();

    short8 af[4], bf[4];
#pragma unroll
    for (int m = 0; m < 4; ++m)
      af[m] = *(const short8*)(Al + ((wr * 64 + m * 16 + tr) * 32 + tg * 8) * 2);
#pragma unroll
    for (int n = 0; n < 4; ++n)
      bf[n] = *(const short8*)(Bl + ((wc * 64 + n * 16 + tr) * 32 + tg * 8) * 2);
#pragma unroll
    for (int m = 0; m < 4; ++m)
#pragma unroll
      for (int n = 0; n < 4; ++n)
        acc[m][n] = __builtin_amdgcn_mfma_f32_16x16x32_bf16(af[m], bf[n], acc[m][n], 0, 0, 0);
    __syncthreads();
  }

  if (EPI == 0) {  // bf16 out (+optional bias): Q, K projections
    unsigned short* C = (unsigned short*)Cout + (long)bz * sC;
#pragma unroll
    for (int n = 0; n < 4; ++n) {
      const int col = cbase + wc * 64 + n * 16 + tr;
      const float bv = ep.bias ? ep.bias[col] : 0.f;
#pragma unroll
      for (int m = 0; m < 4; ++m) {
#pragma unroll
        for (int i = 0; i < 4; ++i) {
          const int row = rbase + wr * 64 + m * 16 + tg * 4 + i;
          C[(long)row * ldc + col] = f2bf(acc[m][n][i] + bv);
        }
      }
    }
  } else if (EPI == 1) {  // V-projection writing V^T: Vt[b][e][m]
    unsigned short* C = (unsigned short*)Cout;
#pragma unroll
    for (int n = 0; n < 4; ++n) {
      const int col = cbase + wc * 64 + n * 16 + tr;
      const float bv = ep.bias ? ep.bias[col] : 0.f;
#pragma unroll
      for (int m = 0; m < 4; ++m) {
        const int row0 = rbase + wr * 64 + m * 16 + tg * 4;
        const int b  = row0 >> 11;
        const int ml = row0 & 2047;
        us4 v;
#pragma unroll
        for (int i = 0; i < 4; ++i) v[i] = f2bf(acc[m][n][i] + bv);
        *(us4*)(C + ((long)b * 512 + col) * 2048 + ml) = v;
      }
    }
  } else {  // EPI 3: fp32 out = acc + bias + residual(query_feat)
    float* C = (float*)Cout;
    const float* qf = ep.aux0;
#pragma unroll
    for (int n = 0; n < 4; ++n) {
      const int col = cbase + wc * 64 + n * 16 + tr;
      const float bv = ep.bias ? ep.bias[col] : 0.f;
#pragma unroll
      for (int m = 0; m < 4; ++m) {
#pragma unroll
        for (int i = 0; i < 4; ++i) {
          const int row = rbase + wr * 64 + m * 16 + tg * 4 + i;
          C[(long)row * 512 + col] = acc[m][n][i] + bv + qf[(long)row * 512 + col];
        }
      }
    }
  }
}

// ---------- big-tile GEMM: 256x128, XCD-pinned batches ----------
// NWC = wave-grid cols (2 -> 256 threads, NF=4; 4 -> 512 threads, NF=2).
// Wave tile = 128 rows x (NF*16) cols; acc[8][NF].
// grid: (8 batches [-> XCD], rowTiles*ntn). EPI 0: bf16 C out. EPI 2: scores epilogue.
template<int EPI, int NWC>
__global__ __launch_bounds__(128 * NWC, 2)
void gemm_big(const unsigned short* __restrict__ A, const unsigned short* __restrict__ B,
              void* __restrict__ Cout, int Kd, int lda, int ldb, int ldc,
              long sA, long sB, long sC, int ntn, EpiParams ep)
{
  constexpr int T  = 128 * NWC;
  constexpr int NF = 128 / (NWC * 16);
  constexpr int RA = 16384 / (T * 16);   // A tile 256x32x2B = 16 KB
  constexpr int RB = 8192 / (T * 16);    // B tile 128x32x2B = 8 KB

  __shared__ __attribute__((aligned(16))) char smem[24576];
  char* Al = smem;
  char* Bl = smem + 16384;

  const int t    = threadIdx.x;
  const int lane = t & 63;
  const int wid  = t >> 6;
  const int wr   = wid / NWC;
  const int wc   = wid % NWC;
  const int tr   = lane & 15;
  const int tg   = lane >> 4;

  const int bz    = blockIdx.x;                   // batch -> XCD (gridDim.x == 8)
  const int rbase = (blockIdx.y / ntn) * 256;
  const int cbase = (blockIdx.y % ntn) * 128;

  const unsigned short* Ab = A + (long)bz * sA;
  const unsigned short* Bb = B + (long)bz * sB;
  const char* Asrc = (const char*)(Ab + (long)rbase * lda);
  const char* Bsrc = (const char*)(Bb + (long)cbase * ldb);
  const long lda_b = (long)lda * 2;
  const long ldb_b = (long)ldb * 2;

  f32x4 acc[8][NF] = {};

  for (int k0 = 0; k0 < Kd; k0 += BK) {
#pragma unroll
    for (int r = 0; r < RA; ++r) {
      const int o = (r * T + t) * 16;
      gload16(Asrc + (long)(o >> 6) * lda_b + (k0 * 2 + (o & 63)),
              Al + (r * T + wid * 64) * 16);
    }
#pragma unroll
    for (int r = 0; r < RB; ++r) {
      const int o = (r * T + t) * 16;
      gload16(Bsrc + (long)(o >> 6) * ldb_b + (k0 * 2 + (o & 63)),
              Bl + (r * T + wid * 64) * 16);
    }
    __syncthreads();

    short8 af[8], bf[NF];
#pragma unroll
    for (int m = 0; m < 8; ++m)
      af[m] = *(const short8*)(Al + ((wr * 128 + m * 16 + tr) * 32 + tg * 8) * 2);
#pragma unroll
    for (int n = 0; n < NF; ++n)
      bf[n] = *(const short8*)(Bl + ((wc * (NF * 16) + n * 16 + tr) * 32 + tg * 8) * 2);
#pragma unroll
    for (int m = 0; m < 8; ++m)
#pragma unroll
      for (int n = 0; n < NF; ++n)
        acc[m][n] = __builtin_amdgcn_mfma_f32_16x16x32_bf16(af[m], bf[n], acc[m][n], 0, 0, 0);
    __syncthreads();
  }

  if (EPI == 0) {  // bf16 out, no bias (PV)
    unsigned short* C = (unsigned short*)Cout + (long)bz * sC;
#pragma unroll
    for (int n = 0; n < NF; ++n) {
      const int col = cbase + wc * (NF * 16) + n * 16 + tr;
#pragma unroll
      for (int m = 0; m < 8; ++m) {
#pragma unroll
        for (int i = 0; i < 4; ++i) {
          const int row = rbase + wr * 128 + m * 16 + tg * 4 + i;
          C[(long)row * ldc + col] = f2bf(acc[m][n][i]);
        }
      }
    }
  } else {  // EPI 2: scores epilogue (NWC==2, T==256 only)
    float* qs = (float*)smem;          // 256*3 floats
    float* ks = (float*)smem + 768;    // 128*3 floats
    {
      const float* q = ep.aux0 + (long)bz * ep.saux + (long)(rbase + t) * 3;
      qs[t * 3] = q[0]; qs[t * 3 + 1] = q[1]; qs[t * 3 + 2] = q[2];
      if (t < 128) {
        const float* k2 = ep.aux1 + (long)bz * ep.saux + (long)(cbase + t) * 3;
        ks[t * 3] = k2[0]; ks[t * 3 + 1] = k2[1]; ks[t * 3 + 2] = k2[2];
      }
    }
    __syncthreads();
    unsigned short* C = (unsigned short*)Cout + (long)bz * sC;
#pragma unroll
    for (int m = 0; m < 8; ++m) {
#pragma unroll
      for (int i = 0; i < 4; ++i) {
        const int rl = wr * 128 + m * 16 + tg * 4 + i;
        const float qx = qs[rl * 3], qy = qs[rl * 3 + 1], qz = qs[rl * 3 + 2];
#pragma unroll
        for (int n = 0; n < NF; ++n) {
          const int cl = wc * (NF * 16) + n * 16 + tr;
          const float dx = qx - ks[cl * 3];
          const float dy = qy - ks[cl * 3 + 1];
          const float dz = qz - ks[cl * 3 + 2];
          const float d2 = dx * dx + dy * dy + dz * dz;
          const float d  = sqrtf(fmaxf(d2, 1e-12f));
          // log(exp(-2d)+1e-8) ~= max(-2d, ln(1e-8))
          const float bias = fmaxf(-2.f * d, -18.420680743952367f);
          C[(long)(rbase + rl) * ldc + (cbase + cl)] = f2bf(acc[m][n][i] * ep.scale + bias);
        }
      }
    }
  }
}

// in-place row softmax on bf16 S rows of length 2048; one wave per row
__global__ __launch_bounds__(256)
void softmax_rows(unsigned short* __restrict__ S)
{
  const int row  = blockIdx.x * 4 + (threadIdx.x >> 6);
  const int lane = threadIdx.x & 63;
  unsigned short* rp = S + (long)row * 2048;

  us8 v[4];
#pragma unroll
  for (int c = 0; c < 4; ++c) v[c] = *(const us8*)(rp + c * 512 + lane * 8);
  float f[32];
#pragma unroll
  for (int c = 0; c < 4; ++c)
#pragma unroll
    for (int j = 0; j < 8; ++j) f[c * 8 + j] = bf2f(v[c][j]);

  float mx = f[0];
#pragma unroll
  for (int i = 1; i < 32; ++i) mx = fmaxf(mx, f[i]);
#pragma unroll
  for (int off = 32; off; off >>= 1) mx = fmaxf(mx, __shfl_xor(mx, off, 64));

  float sum = 0.f;
#pragma unroll
  for (int i = 0; i < 32; ++i) { f[i] = __expf(f[i] - mx); sum += f[i]; }
#pragma unroll
  for (int off = 32; off; off >>= 1) sum += __shfl_xor(sum, off, 64);
  const float inv = 1.f / sum;

#pragma unroll
  for (int c = 0; c < 4; ++c) {
    us8 o;
#pragma unroll
    for (int j = 0; j < 8; ++j) o[j] = f2bf(f[c * 8 + j] * inv);
    *(us8*)(rp + c * 512 + lane * 8) = o;
  }
}

// LayerNorm rows of 512 fp32; one wave per row
__global__ __launch_bounds__(256)
void ln_rows(const float* __restrict__ X, const float* __restrict__ g,
             const float* __restrict__ b, float* __restrict__ O)
{
  const int row  = blockIdx.x * 4 + (threadIdx.x >> 6);
  const int lane = threadIdx.x & 63;
  const float* xp = X + (long)row * 512;

  f32x4 v0 = *(const f32x4*)(xp + lane * 4);
  f32x4 v1 = *(const f32x4*)(xp + 256 + lane * 4);

  float s = 0.f;
#pragma unroll
  for (int j = 0; j < 4; ++j) s += v0[j] + v1[j];
#pragma unroll
  for (int off = 32; off; off >>= 1) s += __shfl_xor(s, off, 64);
  const float mu = s * (1.f / 512.f);

  float vs = 0.f;
#pragma unroll
  for (int j = 0; j < 4; ++j) {
    float d0 = v0[j] - mu, d1 = v1[j] - mu;
    vs += d0 * d0 + d1 * d1;
  }
#pragma unroll
  for (int off = 32; off; off >>= 1) vs += __shfl_xor(vs, off, 64);
  const float r = rsqrtf(vs * (1.f / 512.f) + 1e-5f);

  f32x4 g0 = *(const f32x4*)(g + lane * 4);
  f32x4 g1 = *(const f32x4*)(g + 256 + lane * 4);
  f32x4 b0 = *(const f32x4*)(b + lane * 4);
  f32x4 b1 = *(const f32x4*)(b + 256 + lane * 4);

  f32x4 o0, o1;
#pragma unroll
  for (int j = 0; j < 4; ++j) {
    o0[j] = (v0[j] - mu) * r * g0[j] + b0[j];
    o1[j] = (v1[j] - mu) * r * g1[j] + b1[j];
  }
  float* op = O + (long)row * 512;
  *(f32x4*)(op + lane * 4) = o0;
  *(f32x4*)(op + 256 + lane * 4) = o1;
}

// fp32 -> bf16, 8 elements per thread
__global__ __launch_bounds__(256)
void cvt_bf16(const float* __restrict__ src, unsigned short* __restrict__ dst, int nvec)
{
  const int i = blockIdx.x * blockDim.x + threadIdx.x;
  if (i >= nvec) return;
  const f32x4* s = (const f32x4*)src;
  f32x4 a = s[(long)i * 2];
  f32x4 c = s[(long)i * 2 + 1];
  us8 o;
#pragma unroll
  for (int j = 0; j < 4; ++j) { o[j] = f2bf(a[j]); o[4 + j] = f2bf(c[j]); }
  *(us8*)(dst + (long)i * 8) = o;
}

extern "C" void kernel_launch(void* const* d_in, const int* in_sizes, int n_in,
                              void* d_out, int out_size, void* d_ws, size_t ws_size,
                              hipStream_t stream)
{
  const float* qxyz  = (const float*)d_in[0];
  const float* qfeat = (const float*)d_in[1];
  const float* kxyz  = (const float*)d_in[2];
  const float* kfeat = (const float*)d_in[3];
  const float* Wq = (const float*)d_in[4];
  const float* bq = (const float*)d_in[5];
  const float* Wk = (const float*)d_in[6];
  const float* bk = (const float*)d_in[7];
  const float* Wv = (const float*)d_in[8];
  const float* bv = (const float*)d_in[9];
  const float* Wo = (const float*)d_in[10];
  const float* bo = (const float*)d_in[11];
  const float* lng = (const float*)d_in[12];
  const float* lnb = (const float*)d_in[13];

  const long SZ_FEAT = 16777216;            // 8*2048*512*2
  char* ws = (char*)d_ws;
  if (ws_size < (size_t)153092096) return;  // need ~153 MB

  unsigned short* XQ  = (unsigned short*)(ws);
  unsigned short* XK  = (unsigned short*)(ws + SZ_FEAT);
  unsigned short* QB  = (unsigned short*)(ws + 2 * SZ_FEAT);
  unsigned short* KB  = (unsigned short*)(ws + 3 * SZ_FEAT);
  unsigned short* VT  = (unsigned short*)(ws + 4 * SZ_FEAT);
  unsigned short* WQB = (unsigned short*)(ws + 5 * SZ_FEAT);
  unsigned short* WKB = WQB + 262144;
  unsigned short* WVB = WQB + 524288;
  unsigned short* WOB = WQB + 786432;
  unsigned short* SB  = (unsigned short*)(ws + 5 * SZ_FEAT + 2097152);
  unsigned short* ATT = QB;                 // alias: Q dead after scores GEMM
  float* XRES = (float*)ws;                 // alias: XQ/XK dead after projections

  // 1. conversions
  cvt_bf16<<<4096, 256, 0, stream>>>(qfeat, XQ, 1048576);
  cvt_bf16<<<4096, 256, 0, stream>>>(kfeat, XK, 1048576);
  cvt_bf16<<<128, 256, 0, stream>>>(Wq, WQB, 32768);
  cvt_bf16<<<128, 256, 0, stream>>>(Wk, WKB, 32768);
  cvt_bf16<<<128, 256, 0, stream>>>(Wv, WVB, 32768);
  cvt_bf16<<<128, 256, 0, stream>>>(Wo, WOB, 32768);

  // 2. projections (128^2 tiles)
  EpiParams e0{}; e0.bias = bq;
  gemm_bt<0><<<dim3(4, 128, 1), 256, 0, stream>>>(XQ, WQB, QB, 512, 512, 512, 512, 0, 0, 0, e0);
  EpiParams e1{}; e1.bias = bk;
  gemm_bt<0><<<dim3(4, 128, 1), 256, 0, stream>>>(XK, WKB, KB, 512, 512, 512, 512, 0, 0, 0, e1);
  EpiParams e2{}; e2.bias = bv;
  gemm_bt<1><<<dim3(4, 128, 1), 256, 0, stream>>>(XK, WVB, VT, 512, 512, 512, 0, 0, 0, 0, e2);

  // 3. scores + distance bias: 256x128 tiles, batch->XCD pinned
  EpiParams es{}; es.aux0 = qxyz; es.aux1 = kxyz; es.saux = 2048 * 3;
  es.scale = 0.044194173824159216f;  // 1/sqrt(512)
  gemm_big<2, 2><<<dim3(8, 128), 256, 0, stream>>>(QB, KB, SB, 512, 512, 512, 2048,
                                                   (long)2048 * 512, (long)2048 * 512,
                                                   (long)2048 * 2048, 16, es);

  // 4. softmax
  softmax_rows<<<4096, 256, 0, stream>>>(SB);

  // 5. attended = P @ V (via Vt): 256x128 tiles, batch->XCD pinned
  EpiParams ep{};
  gemm_big<0, 4><<<dim3(8, 32), 512, 0, stream>>>(SB, VT, ATT, 2048, 2048, 2048, 512,
                                                  (long)2048 * 2048, (long)512 * 2048,
                                                  (long)2048 * 512, 4, ep);

  // 6. out projection + bias + residual -> x (fp32)
  EpiParams eo{}; eo.bias = bo; eo.aux0 = qfeat;
  gemm_bt<3><<<dim3(4, 128, 1), 256, 0, stream>>>(ATT, WOB, XRES, 512, 512, 512, 512, 0, 0, 0, eo);

  // 7. LayerNorm -> out
  ln_rows<<<4096, 256, 0, stream>>>(XRES, lng, lnb, (float*)d_out);
}

// Round 4
// 277.211 us; speedup vs baseline: 1.4184x; 1.0082x over previous
//
#include <hip/hip_runtime.h>

typedef __attribute__((ext_vector_type(8))) short short8;
typedef __attribute__((ext_vector_type(8))) unsigned short us8;
typedef __attribute__((ext_vector_type(4))) unsigned short us4;
typedef __attribute__((ext_vector_type(4))) float f32x4;

__device__ __forceinline__ float bf2f(unsigned short h) {
  return __uint_as_float(((unsigned int)h) << 16);
}
__device__ __forceinline__ unsigned short f2bf(float f) {
  unsigned int u = __float_as_uint(f);
  u += 0x7FFF + ((u >> 16) & 1);
  return (unsigned short)(u >> 16);
}

// async global->LDS, 16B per lane. LDS dest is wave-uniform base + lane*16.
__device__ __forceinline__ void gload16(const void* g, void* l) {
  __builtin_amdgcn_global_load_lds(
      (const __attribute__((address_space(1))) unsigned int*)g,
      (__attribute__((address_space(3))) unsigned int*)l, 16, 0, 0);
}

#define BM 128
#define BN 128
#define BK 32

struct EpiParams {
  const float* bias;   // [out cols] or null
  const float* aux0;   // EPI2: query_xyz ; EPI3: query_feat (residual)
  const float* aux1;   // EPI2: key_xyz  ; EPI4: bv
  const void*  aux2;   // EPI2/EPI0big: lsum ; EPI4: VT dest
  long  saux;          // xyz batch stride (elements)
  float scale;         // EPI2: 1/sqrt(D)
};

// ---------- small-tile GEMM (projections / out-proj) ----------
// C[r][c] = sum_k A[r][k] * B[c][k]
template<int EPI>
__global__ __launch_bounds__(256)
void gemm_bt(const unsigned short* __restrict__ A, const unsigned short* __restrict__ B,
             void* __restrict__ Cout, int Kd, int lda, int ldb, int ldc,
             long sA, long sB, long sC, EpiParams ep)
{
  __shared__ __attribute__((aligned(16))) char smem[16384];
  char* Al = smem;
  char* Bl = smem + 8192;

  const int t    = threadIdx.x;
  const int lane = t & 63;
  const int wid  = t >> 6;
  const int wr   = wid >> 1;
  const int wc   = wid & 1;
  const int tr   = lane & 15;
  const int tg   = lane >> 4;

  const int bz    = blockIdx.z;
  const int rbase = blockIdx.y * BM;
  const int cbase = blockIdx.x * BN;

  const unsigned short* Ab = A + (long)bz * sA;
  const unsigned short* Bb = B + (long)bz * sB;
  const char* Asrc = (const char*)(Ab + (long)rbase * lda);
  const char* Bsrc = (const char*)(Bb + (long)cbase * ldb);
  const long lda_b = (long)lda * 2;
  const long ldb_b = (long)ldb * 2;

  f32x4 acc[4][4] = {};

  for (int k0 = 0; k0 < Kd; k0 += BK) {
#pragma unroll
    for (int it = 0; it < 2; ++it) {
      const int boff = (it * 4 + wid) * 1024 + lane * 16;
      const int r  = boff >> 6;
      const int cb = boff & 63;
      gload16(Asrc + (long)r * lda_b + (k0 * 2 + cb), Al + (it * 4 + wid) * 1024);
      gload16(Bsrc + (long)r * ldb_b + (k0 * 2 + cb), Bl + (it * 4 + wid) * 1024);
    }
    __syncthreads();

    short8 af[4], bf[4];
#pragma unroll
    for (int m = 0; m < 4; ++m)
      af[m] = *(const short8*)(Al + ((wr * 64 + m * 16 + tr) * 32 + tg * 8) * 2);
#pragma unroll
    for (int n = 0; n < 4; ++n)
      bf[n] = *(const short8*)(Bl + ((wc * 64 + n * 16 + tr) * 32 + tg * 8) * 2);
#pragma unroll
    for (int m = 0; m < 4; ++m)
#pragma unroll
      for (int n = 0; n < 4; ++n)
        acc[m][n] = __builtin_amdgcn_mfma_f32_16x16x32_bf16(af[m], bf[n], acc[m][n], 0, 0, 0);
    __syncthreads();
  }

  if (EPI == 0) {  // bf16 out (+optional bias): Q projection
    unsigned short* C = (unsigned short*)Cout + (long)bz * sC;
#pragma unroll
    for (int n = 0; n < 4; ++n) {
      const int col = cbase + wc * 64 + n * 16 + tr;
      const float bv = ep.bias ? ep.bias[col] : 0.f;
#pragma unroll
      for (int m = 0; m < 4; ++m) {
#pragma unroll
        for (int i = 0; i < 4; ++i) {
          const int row = rbase + wr * 64 + m * 16 + tg * 4 + i;
          C[(long)row * ldc + col] = f2bf(acc[m][n][i] + bv);
        }
      }
    }
  } else if (EPI == 4) {  // combined K|V projection: cols<512 -> K, else -> V^T
    if (cbase < 512) {
      unsigned short* C = (unsigned short*)Cout;  // KB, ldc elems = 512
#pragma unroll
      for (int n = 0; n < 4; ++n) {
        const int col = cbase + wc * 64 + n * 16 + tr;
        const float bv = ep.bias[col];
#pragma unroll
        for (int m = 0; m < 4; ++m) {
#pragma unroll
          for (int i = 0; i < 4; ++i) {
            const int row = rbase + wr * 64 + m * 16 + tg * 4 + i;
            C[(long)row * 512 + col] = f2bf(acc[m][n][i] + bv);
          }
        }
      }
    } else {
      unsigned short* C = (unsigned short*)ep.aux2;  // VT
#pragma unroll
      for (int n = 0; n < 4; ++n) {
        const int e  = cbase - 512 + wc * 64 + n * 16 + tr;
        const float bv = ep.aux1[e];
#pragma unroll
        for (int m = 0; m < 4; ++m) {
          const int row0 = rbase + wr * 64 + m * 16 + tg * 4;
          const int b  = row0 >> 11;
          const int ml = row0 & 2047;
          us4 v;
#pragma unroll
          for (int i = 0; i < 4; ++i) v[i] = f2bf(acc[m][n][i] + bv);
          *(us4*)(C + ((long)b * 512 + e) * 2048 + ml) = v;
        }
      }
    }
  } else {  // EPI 3: fp32 out = acc + bias + residual(query_feat)
    float* C = (float*)Cout;
    const float* qf = ep.aux0;
#pragma unroll
    for (int n = 0; n < 4; ++n) {
      const int col = cbase + wc * 64 + n * 16 + tr;
      const float bv = ep.bias ? ep.bias[col] : 0.f;
#pragma unroll
      for (int m = 0; m < 4; ++m) {
#pragma unroll
        for (int i = 0; i < 4; ++i) {
          const int row = rbase + wr * 64 + m * 16 + tg * 4 + i;
          C[(long)row * 512 + col] = acc[m][n][i] + bv + qf[(long)row * 512 + col];
        }
      }
    }
  }
}

// ---------- big-tile GEMM: 256x128, XCD-pinned batches ----------
// NWC = wave-grid cols (2 -> 256 threads, NF=4; 4 -> 512 threads, NF=2).
// EPI 0: PV (bf16 out, divide by row-sum l). EPI 2: scores -> P=exp(s-5) + row-sum atomics.
template<int EPI, int NWC>
__global__ __launch_bounds__(128 * NWC, 2)
void gemm_big(const unsigned short* __restrict__ A, const unsigned short* __restrict__ B,
              void* __restrict__ Cout, int Kd, int lda, int ldb, int ldc,
              long sA, long sB, long sC, int ntn, EpiParams ep)
{
  constexpr int T  = 128 * NWC;
  constexpr int NF = 128 / (NWC * 16);
  constexpr int RA = 16384 / (T * 16);   // A tile 256x32x2B = 16 KB
  constexpr int RB = 8192 / (T * 16);    // B tile 128x32x2B = 8 KB

  __shared__ __attribute__((aligned(16))) char smem[24576];
  char* Al = smem;
  char* Bl = smem + 16384;

  const int t    = threadIdx.x;
  const int lane = t & 63;
  const int wid  = t >> 6;
  const int wr   = wid / NWC;
  const int wc   = wid % NWC;
  const int tr   = lane & 15;
  const int tg   = lane >> 4;

  const int bz    = blockIdx.x;                   // batch -> XCD (gridDim.x == 8)
  const int rbase = (blockIdx.y / ntn) * 256;
  const int cbase = (blockIdx.y % ntn) * 128;

  const unsigned short* Ab = A + (long)bz * sA;
  const unsigned short* Bb = B + (long)bz * sB;
  const char* Asrc = (const char*)(Ab + (long)rbase * lda);
  const char* Bsrc = (const char*)(Bb + (long)cbase * ldb);
  const long lda_b = (long)lda * 2;
  const long ldb_b = (long)ldb * 2;

  f32x4 acc[8][NF] = {};

  for (int k0 = 0; k0 < Kd; k0 += BK) {
#pragma unroll
    for (int r = 0; r < RA; ++r) {
      const int o = (r * T + t) * 16;
      gload16(Asrc + (long)(o >> 6) * lda_b + (k0 * 2 + (o & 63)),
              Al + (r * T + wid * 64) * 16);
    }
#pragma unroll
    for (int r = 0; r < RB; ++r) {
      const int o = (r * T + t) * 16;
      gload16(Bsrc + (long)(o >> 6) * ldb_b + (k0 * 2 + (o & 63)),
              Bl + (r * T + wid * 64) * 16);
    }
    __syncthreads();

    short8 af[8], bf[NF];
#pragma unroll
    for (int m = 0; m < 8; ++m)
      af[m] = *(const short8*)(Al + ((wr * 128 + m * 16 + tr) * 32 + tg * 8) * 2);
#pragma unroll
    for (int n = 0; n < NF; ++n)
      bf[n] = *(const short8*)(Bl + ((wc * (NF * 16) + n * 16 + tr) * 32 + tg * 8) * 2);
#pragma unroll
    for (int m = 0; m < 8; ++m)
#pragma unroll
      for (int n = 0; n < NF; ++n)
        acc[m][n] = __builtin_amdgcn_mfma_f32_16x16x32_bf16(af[m], bf[n], acc[m][n], 0, 0, 0);
    __syncthreads();
  }

  if (EPI == 0) {  // PV out: bf16, divided by row sum l
    unsigned short* C = (unsigned short*)Cout + (long)bz * sC;
    const float* ls = (const float*)ep.aux2 + (long)bz * 2048 + rbase;
#pragma unroll
    for (int m = 0; m < 8; ++m) {
      const f32x4 lv = *(const f32x4*)(ls + wr * 128 + m * 16 + tg * 4);
      f32x4 inv;
#pragma unroll
      for (int i = 0; i < 4; ++i) inv[i] = 1.f / lv[i];
#pragma unroll
      for (int n = 0; n < NF; ++n) {
        const int col = cbase + wc * (NF * 16) + n * 16 + tr;
#pragma unroll
        for (int i = 0; i < 4; ++i) {
          const int row = rbase + wr * 128 + m * 16 + tg * 4 + i;
          C[(long)row * ldc + col] = f2bf(acc[m][n][i] * inv[i]);
        }
      }
    }
  } else {  // EPI 2: P = exp(s - 5) + per-row sum atomics (no-max-sub softmax)
    float* qs = (float*)smem;          // 256*3 floats
    float* ks = (float*)smem + 768;    // 128*3 floats
    {
      const float* q = ep.aux0 + (long)bz * ep.saux + (long)(rbase + t) * 3;
      qs[t * 3] = q[0]; qs[t * 3 + 1] = q[1]; qs[t * 3 + 2] = q[2];
      if (t < 128) {
        const float* k2 = ep.aux1 + (long)bz * ep.saux + (long)(cbase + t) * 3;
        ks[t * 3] = k2[0]; ks[t * 3 + 1] = k2[1]; ks[t * 3 + 2] = k2[2];
      }
    }
    __syncthreads();
    unsigned short* C = (unsigned short*)Cout + (long)bz * sC;
    float* lrow = (float*)ep.aux2 + (long)bz * 2048 + rbase;
    float ps[8][4];
#pragma unroll
    for (int m = 0; m < 8; ++m) {
#pragma unroll
      for (int i = 0; i < 4; ++i) {
        ps[m][i] = 0.f;
        const int rl = wr * 128 + m * 16 + tg * 4 + i;
        const float qx = qs[rl * 3], qy = qs[rl * 3 + 1], qz = qs[rl * 3 + 2];
#pragma unroll
        for (int n = 0; n < NF; ++n) {
          const int cl = wc * (NF * 16) + n * 16 + tr;
          const float dx = qx - ks[cl * 3];
          const float dy = qy - ks[cl * 3 + 1];
          const float dz = qz - ks[cl * 3 + 2];
          const float d2 = dx * dx + dy * dy + dz * dz;
          const float d  = sqrtf(fmaxf(d2, 1e-12f));
          // log(exp(-2d)+1e-8) ~= max(-2d, ln(1e-8)); then shifted exp
          const float bias = fmaxf(-2.f * d, -18.420680743952367f);
          const float p = __expf(acc[m][n][i] * ep.scale + bias - 5.f);
          ps[m][i] += p;
          C[(long)(rbase + rl) * ldc + (cbase + cl)] = f2bf(p);
        }
      }
    }
    // reduce partial sums over the 16 tr-lanes (cols), then atomicAdd per row
#pragma unroll
    for (int off = 1; off <= 8; off <<= 1)
#pragma unroll
      for (int m = 0; m < 8; ++m)
#pragma unroll
        for (int i = 0; i < 4; ++i)
          ps[m][i] += __shfl_xor(ps[m][i], off, 64);
    if (tr == 0) {
#pragma unroll
      for (int m = 0; m < 8; ++m)
#pragma unroll
        for (int i = 0; i < 4; ++i)
          atomicAdd(&lrow[wr * 128 + m * 16 + tg * 4 + i], ps[m][i]);
    }
  }
}

// LayerNorm rows of 512 fp32; one wave per row
__global__ __launch_bounds__(256)
void ln_rows(const float* __restrict__ X, const float* __restrict__ g,
             const float* __restrict__ b, float* __restrict__ O)
{
  const int row  = blockIdx.x * 4 + (threadIdx.x >> 6);
  const int lane = threadIdx.x & 63;
  const float* xp = X + (long)row * 512;

  f32x4 v0 = *(const f32x4*)(xp + lane * 4);
  f32x4 v1 = *(const f32x4*)(xp + 256 + lane * 4);

  float s = 0.f;
#pragma unroll
  for (int j = 0; j < 4; ++j) s += v0[j] + v1[j];
#pragma unroll
  for (int off = 32; off; off >>= 1) s += __shfl_xor(s, off, 64);
  const float mu = s * (1.f / 512.f);

  float vs = 0.f;
#pragma unroll
  for (int j = 0; j < 4; ++j) {
    float d0 = v0[j] - mu, d1 = v1[j] - mu;
    vs += d0 * d0 + d1 * d1;
  }
#pragma unroll
  for (int off = 32; off; off >>= 1) vs += __shfl_xor(vs, off, 64);
  const float r = rsqrtf(vs * (1.f / 512.f) + 1e-5f);

  f32x4 g0 = *(const f32x4*)(g + lane * 4);
  f32x4 g1 = *(const f32x4*)(g + 256 + lane * 4);
  f32x4 b0 = *(const f32x4*)(b + lane * 4);
  f32x4 b1 = *(const f32x4*)(b + 256 + lane * 4);

  f32x4 o0, o1;
#pragma unroll
  for (int j = 0; j < 4; ++j) {
    o0[j] = (v0[j] - mu) * r * g0[j] + b0[j];
    o1[j] = (v1[j] - mu) * r * g1[j] + b1[j];
  }
  float* op = O + (long)row * 512;
  *(f32x4*)(op + lane * 4) = o0;
  *(f32x4*)(op + 256 + lane * 4) = o1;
}

// fp32 -> bf16 for the two feature tensors (blockIdx.y selects)
__global__ __launch_bounds__(256)
void cvt_feat(const float* __restrict__ a, const float* __restrict__ b,
              unsigned short* __restrict__ oa, unsigned short* __restrict__ ob)
{
  const float* src = blockIdx.y ? b : a;
  unsigned short* dst = blockIdx.y ? ob : oa;
  const long i = blockIdx.x * 256 + threadIdx.x;
  const f32x4* s = (const f32x4*)src;
  f32x4 x = s[i * 2];
  f32x4 y = s[i * 2 + 1];
  us8 o;
#pragma unroll
  for (int j = 0; j < 4; ++j) { o[j] = f2bf(x[j]); o[4 + j] = f2bf(y[j]); }
  *(us8*)(dst + i * 8) = o;
}

// fp32 -> bf16 for the four weight matrices into one contiguous dst
__global__ __launch_bounds__(256)
void cvt_w(const float* __restrict__ w0, const float* __restrict__ w1,
           const float* __restrict__ w2, const float* __restrict__ w3,
           unsigned short* __restrict__ dst)
{
  const float* src = blockIdx.y == 0 ? w0 : blockIdx.y == 1 ? w1 : blockIdx.y == 2 ? w2 : w3;
  unsigned short* d = dst + (long)blockIdx.y * 262144;
  const long i = blockIdx.x * 256 + threadIdx.x;
  const f32x4* s = (const f32x4*)src;
  f32x4 x = s[i * 2];
  f32x4 y = s[i * 2 + 1];
  us8 o;
#pragma unroll
  for (int j = 0; j < 4; ++j) { o[j] = f2bf(x[j]); o[4 + j] = f2bf(y[j]); }
  *(us8*)(d + i * 8) = o;
}

extern "C" void kernel_launch(void* const* d_in, const int* in_sizes, int n_in,
                              void* d_out, int out_size, void* d_ws, size_t ws_size,
                              hipStream_t stream)
{
  const float* qxyz  = (const float*)d_in[0];
  const float* qfeat = (const float*)d_in[1];
  const float* kxyz  = (const float*)d_in[2];
  const float* kfeat = (const float*)d_in[3];
  const float* Wq = (const float*)d_in[4];
  const float* bq = (const float*)d_in[5];
  const float* Wk = (const float*)d_in[6];
  const float* bk = (const float*)d_in[7];
  const float* Wv = (const float*)d_in[8];
  const float* bv = (const float*)d_in[9];
  const float* Wo = (const float*)d_in[10];
  const float* bo = (const float*)d_in[11];
  const float* lng = (const float*)d_in[12];
  const float* lnb = (const float*)d_in[13];

  const long SZ_FEAT = 16777216;            // 8*2048*512*2
  char* ws = (char*)d_ws;
  if (ws_size < (size_t)153092096) return;  // need ~153 MB

  unsigned short* XQ  = (unsigned short*)(ws);
  unsigned short* XK  = (unsigned short*)(ws + SZ_FEAT);
  unsigned short* QB  = (unsigned short*)(ws + 2 * SZ_FEAT);
  unsigned short* KB  = (unsigned short*)(ws + 3 * SZ_FEAT);
  unsigned short* VT  = (unsigned short*)(ws + 4 * SZ_FEAT);
  unsigned short* WQB = (unsigned short*)(ws + 5 * SZ_FEAT);
  unsigned short* WKB = WQB + 262144;       // contiguous K|V weight block [1024][512]
  unsigned short* WOB = WQB + 786432;
  unsigned short* SB  = (unsigned short*)(ws + 5 * SZ_FEAT + 2097152);
  unsigned short* ATT = QB;                 // alias: Q dead after scores GEMM
  float* XRES = (float*)ws;                 // alias: XQ/XK dead after projections
  float* LSUM = (float*)(ws + SZ_FEAT);     // alias: XK dead after KV projection

  // 1. conversions (2 dispatches)
  cvt_feat<<<dim3(4096, 2), 256, 0, stream>>>(qfeat, kfeat, XQ, XK);
  cvt_w<<<dim3(128, 4), 256, 0, stream>>>(Wq, Wk, Wv, Wo, WQB);

  // 2. projections: Q, then combined K|V
  EpiParams e0{}; e0.bias = bq;
  gemm_bt<0><<<dim3(4, 128, 1), 256, 0, stream>>>(XQ, WQB, QB, 512, 512, 512, 512, 0, 0, 0, e0);
  EpiParams e1{}; e1.bias = bk; e1.aux1 = bv; e1.aux2 = VT;
  gemm_bt<4><<<dim3(8, 128, 1), 256, 0, stream>>>(XK, WKB, KB, 512, 512, 512, 512, 0, 0, 0, e1);

  // zero row-sum buffer (XK region now dead)
  hipMemsetAsync(LSUM, 0, 8 * 2048 * sizeof(float), stream);

  // 3. scores -> P = exp(s-5), row sums via atomics; 256x128 tiles, batch->XCD pinned
  EpiParams es{}; es.aux0 = qxyz; es.aux1 = kxyz; es.aux2 = LSUM; es.saux = 2048 * 3;
  es.scale = 0.044194173824159216f;  // 1/sqrt(512)
  gemm_big<2, 2><<<dim3(8, 128), 256, 0, stream>>>(QB, KB, SB, 512, 512, 512, 2048,
                                                   (long)2048 * 512, (long)2048 * 512,
                                                   (long)2048 * 2048, 16, es);

  // 4. attended = (P @ V) / l : 256x128 tiles, batch->XCD pinned
  EpiParams ep{}; ep.aux2 = LSUM;
  gemm_big<0, 4><<<dim3(8, 32), 512, 0, stream>>>(SB, VT, ATT, 2048, 2048, 2048, 512,
                                                  (long)2048 * 2048, (long)512 * 2048,
                                                  (long)2048 * 512, 4, ep);

  // 5. out projection + bias + residual -> x (fp32)
  EpiParams eo{}; eo.bias = bo; eo.aux0 = qfeat;
  gemm_bt<3><<<dim3(4, 128, 1), 256, 0, stream>>>(ATT, WOB, XRES, 512, 512, 512, 512, 0, 0, 0, eo);

  // 6. LayerNorm -> out
  ln_rows<<<4096, 256, 0, stream>>>(XRES, lng, lnb, (float*)d_out);
}

// Round 5
// 261.525 us; speedup vs baseline: 1.5034x; 1.0600x over previous
//
#include <hip/hip_runtime.h>

typedef __attribute__((ext_vector_type(8))) short short8;
typedef __attribute__((ext_vector_type(8))) unsigned short us8;
typedef __attribute__((ext_vector_type(4))) unsigned short us4;
typedef __attribute__((ext_vector_type(4))) float f32x4;

__device__ __forceinline__ float bf2f(unsigned short h) {
  return __uint_as_float(((unsigned int)h) << 16);
}
__device__ __forceinline__ unsigned short f2bf(float f) {
  unsigned int u = __float_as_uint(f);
  u += 0x7FFF + ((u >> 16) & 1);
  return (unsigned short)(u >> 16);
}

// async global->LDS, 16B per lane. LDS dest is wave-uniform base + lane*16.
__device__ __forceinline__ void gload16(const void* g, void* l) {
  __builtin_amdgcn_global_load_lds(
      (const __attribute__((address_space(1))) unsigned int*)g,
      (__attribute__((address_space(3))) unsigned int*)l, 16, 0, 0);
}

#define BM 128
#define BN 128
#define BK 32

struct EpiParams {
  const float* bias;   // [out cols] or null
  const float* aux0;   // EPI2: query_xyz ; EPI3: query_feat (residual)
  const float* aux1;   // EPI2: key_xyz  ; EPI4: bv
  const void*  aux2;   // EPI2/EPI0: lsum ; EPI4: VT dest
  long  saux;          // xyz batch stride (elements)
  float scale;         // EPI2: 1/sqrt(D)
};

// ---------- small-tile GEMM (projections / out-proj), proven structure ----------
template<int EPI>
__global__ __launch_bounds__(256)
void gemm_bt(const unsigned short* __restrict__ A, const unsigned short* __restrict__ B,
             void* __restrict__ Cout, int Kd, int lda, int ldb, int ldc,
             long sA, long sB, long sC, EpiParams ep)
{
  __shared__ __attribute__((aligned(16))) char smem[16384];
  char* Al = smem;
  char* Bl = smem + 8192;

  const int t    = threadIdx.x;
  const int lane = t & 63;
  const int wid  = t >> 6;
  const int wr   = wid >> 1;
  const int wc   = wid & 1;
  const int tr   = lane & 15;
  const int tg   = lane >> 4;

  const int bz    = blockIdx.z;
  const int rbase = blockIdx.y * BM;
  const int cbase = blockIdx.x * BN;

  const unsigned short* Ab = A + (long)bz * sA;
  const unsigned short* Bb = B + (long)bz * sB;
  const char* Asrc = (const char*)(Ab + (long)rbase * lda);
  const char* Bsrc = (const char*)(Bb + (long)cbase * ldb);
  const long lda_b = (long)lda * 2;
  const long ldb_b = (long)ldb * 2;

  f32x4 acc[4][4] = {};

  for (int k0 = 0; k0 < Kd; k0 += BK) {
#pragma unroll
    for (int it = 0; it < 2; ++it) {
      const int boff = (it * 4 + wid) * 1024 + lane * 16;
      const int r  = boff >> 6;
      const int cb = boff & 63;
      gload16(Asrc + (long)r * lda_b + (k0 * 2 + cb), Al + (it * 4 + wid) * 1024);
      gload16(Bsrc + (long)r * ldb_b + (k0 * 2 + cb), Bl + (it * 4 + wid) * 1024);
    }
    __syncthreads();

    short8 af[4], bf[4];
#pragma unroll
    for (int m = 0; m < 4; ++m)
      af[m] = *(const short8*)(Al + ((wr * 64 + m * 16 + tr) * 32 + tg * 8) * 2);
#pragma unroll
    for (int n = 0; n < 4; ++n)
      bf[n] = *(const short8*)(Bl + ((wc * 64 + n * 16 + tr) * 32 + tg * 8) * 2);
#pragma unroll
    for (int m = 0; m < 4; ++m)
#pragma unroll
      for (int n = 0; n < 4; ++n)
        acc[m][n] = __builtin_amdgcn_mfma_f32_16x16x32_bf16(af[m], bf[n], acc[m][n], 0, 0, 0);
    __syncthreads();
  }

  if (EPI == 0) {  // bf16 out (+optional bias): Q projection
    unsigned short* C = (unsigned short*)Cout + (long)bz * sC;
#pragma unroll
    for (int n = 0; n < 4; ++n) {
      const int col = cbase + wc * 64 + n * 16 + tr;
      const float bv = ep.bias ? ep.bias[col] : 0.f;
#pragma unroll
      for (int m = 0; m < 4; ++m) {
#pragma unroll
        for (int i = 0; i < 4; ++i) {
          const int row = rbase + wr * 64 + m * 16 + tg * 4 + i;
          C[(long)row * ldc + col] = f2bf(acc[m][n][i] + bv);
        }
      }
    }
  } else if (EPI == 4) {  // combined K|V projection: cols<512 -> K, else -> V^T
    if (cbase < 512) {
      unsigned short* C = (unsigned short*)Cout;  // KB
#pragma unroll
      for (int n = 0; n < 4; ++n) {
        const int col = cbase + wc * 64 + n * 16 + tr;
        const float bv = ep.bias[col];
#pragma unroll
        for (int m = 0; m < 4; ++m) {
#pragma unroll
          for (int i = 0; i < 4; ++i) {
            const int row = rbase + wr * 64 + m * 16 + tg * 4 + i;
            C[(long)row * 512 + col] = f2bf(acc[m][n][i] + bv);
          }
        }
      }
    } else {
      unsigned short* C = (unsigned short*)ep.aux2;  // VT
#pragma unroll
      for (int n = 0; n < 4; ++n) {
        const int e  = cbase - 512 + wc * 64 + n * 16 + tr;
        const float bv = ep.aux1[e];
#pragma unroll
        for (int m = 0; m < 4; ++m) {
          const int row0 = rbase + wr * 64 + m * 16 + tg * 4;
          const int b  = row0 >> 11;
          const int ml = row0 & 2047;
          us4 v;
#pragma unroll
          for (int i = 0; i < 4; ++i) v[i] = f2bf(acc[m][n][i] + bv);
          *(us4*)(C + ((long)b * 512 + e) * 2048 + ml) = v;
        }
      }
    }
  } else {  // EPI 3: fp32 out = acc + bias + residual(query_feat)
    float* C = (float*)Cout;
    const float* qf = ep.aux0;
#pragma unroll
    for (int n = 0; n < 4; ++n) {
      const int col = cbase + wc * 64 + n * 16 + tr;
      const float bv = ep.bias ? ep.bias[col] : 0.f;
#pragma unroll
      for (int m = 0; m < 4; ++m) {
#pragma unroll
        for (int i = 0; i < 4; ++i) {
          const int row = rbase + wr * 64 + m * 16 + tg * 4 + i;
          C[(long)row * 512 + col] = acc[m][n][i] + bv + qf[(long)row * 512 + col];
        }
      }
    }
  }
}

// ---------- 2-phase double-buffered GEMM: BM=128, BN=256, BK=64 ----------
// 512 threads = 8 waves (2 wave-rows x 4 wave-cols); wave tile 64x64, acc[4][4].
// LDS: 2 slots x [A 16KB | B 32KB] = 96 KB. XOR-swizzled: phys = r*128 + ((c16^(r&7))*16).
// Staging: linear gload_lds dest + inverse-swizzled GLOBAL source (rule 21).
// Loop: STAGE(t+1, slot^1); compute(t, slot); __syncthreads() (vmcnt0+lgkm0+barrier).
// EPI 0: PV out = bf16(acc / l).  EPI 2: scores -> P=exp(s*scale+bias-5), row-sum atomics.
template<int EPI>
__global__ __launch_bounds__(512, 2)
void gemm2(const unsigned short* __restrict__ A, const unsigned short* __restrict__ B,
           void* __restrict__ Cout, int Kd, int lda, int ldb, int ldc,
           long sA, long sB, long sC, int ntn, EpiParams ep)
{
  __shared__ __attribute__((aligned(16))) char smem[98304];

  const int t    = threadIdx.x;
  const int lane = t & 63;
  const int wid  = t >> 6;
  const int wr   = wid >> 2;   // 0..1
  const int wc   = wid & 3;    // 0..3
  const int tr   = lane & 15;
  const int tg   = lane >> 4;

  const int bz    = blockIdx.x;                 // batch -> XCD (gridDim.x == 8)
  const int rbase = (blockIdx.y / ntn) * 128;
  const int cbase = (blockIdx.y % ntn) * 256;

  const long lda_b = (long)lda * 2;
  const long ldb_b = (long)ldb * 2;
  const char* Asrc = (const char*)(A + (long)bz * sA + (long)rbase * lda);
  const char* Bsrc = (const char*)(B + (long)bz * sB + (long)cbase * ldb);

  // staging: thread t fills physical 16B slot (c*512+t)*16 of each tile.
  // physical slot holds global col16 = (t&7) ^ (row&7); row = c*64 + (t>>3).
  const int srow   = t >> 3;
  const int scol16 = (t & 7) ^ ((t >> 3) & 7);
  const char* gA[2];
  const char* gB[4];
#pragma unroll
  for (int c = 0; c < 2; ++c)
    gA[c] = Asrc + (long)(c * 64 + srow) * lda_b + scol16 * 16;
#pragma unroll
  for (int c = 0; c < 4; ++c)
    gB[c] = Bsrc + (long)(c * 64 + srow) * ldb_b + scol16 * 16;

  f32x4 acc[4][4] = {};
  const int NT = Kd >> 6;
  int slot = 0;

  // prologue: stage K-tile 0 into slot 0
#pragma unroll
  for (int c = 0; c < 2; ++c) gload16(gA[c], smem + c * 8192 + wid * 1024);
#pragma unroll
  for (int c = 0; c < 4; ++c) gload16(gB[c], smem + 16384 + c * 8192 + wid * 1024);
  __syncthreads();

  for (int tk = 0; tk < NT; ++tk) {
    if (tk + 1 < NT) {  // issue next-tile stage BEFORE compute (latency hides under MFMA)
      const int so = (slot ^ 1) * 49152;
      const long adv = (long)(tk + 1) * 128;
#pragma unroll
      for (int c = 0; c < 2; ++c) gload16(gA[c] + adv, smem + so + c * 8192 + wid * 1024);
#pragma unroll
      for (int c = 0; c < 4; ++c) gload16(gB[c] + adv, smem + so + 16384 + c * 8192 + wid * 1024);
    }
    const char* As = smem + slot * 49152;
    const char* Bs = As + 16384;
    const int x7 = tr & 7;
#pragma unroll
    for (int ks = 0; ks < 2; ++ks) {
      const int coff = ((ks * 4 + tg) ^ x7) * 16;
      short8 af[4], bf[4];
#pragma unroll
      for (int m = 0; m < 4; ++m)
        af[m] = *(const short8*)(As + (wr * 64 + m * 16 + tr) * 128 + coff);
#pragma unroll
      for (int n = 0; n < 4; ++n)
        bf[n] = *(const short8*)(Bs + (wc * 64 + n * 16 + tr) * 128 + coff);
#pragma unroll
      for (int m = 0; m < 4; ++m)
#pragma unroll
        for (int n = 0; n < 4; ++n)
          acc[m][n] = __builtin_amdgcn_mfma_f32_16x16x32_bf16(af[m], bf[n], acc[m][n], 0, 0, 0);
    }
    __syncthreads();  // vmcnt(0)+lgkmcnt(0)+barrier: staged landed, all reads done
    slot ^= 1;
  }

  if (EPI == 0) {  // PV: bf16 out, divided by row sum l
    unsigned short* C = (unsigned short*)Cout + (long)bz * sC;
    const float* ls = (const float*)ep.aux2 + (long)bz * 2048 + rbase + wr * 64;
#pragma unroll
    for (int m = 0; m < 4; ++m) {
      const f32x4 lv = *(const f32x4*)(ls + m * 16 + tg * 4);
      f32x4 inv;
#pragma unroll
      for (int i = 0; i < 4; ++i) inv[i] = 1.f / lv[i];
#pragma unroll
      for (int n = 0; n < 4; ++n) {
        const int col = cbase + wc * 64 + n * 16 + tr;
#pragma unroll
        for (int i = 0; i < 4; ++i) {
          const int row = rbase + wr * 64 + m * 16 + tg * 4 + i;
          C[(long)row * ldc + col] = f2bf(acc[m][n][i] * inv[i]);
        }
      }
    }
  } else {  // EPI 2: P = exp(s*scale + distbias - 5) + per-row sum atomics
    float* qs  = (float*)smem;          // 128*3 floats
    float* ks2 = (float*)smem + 384;    // 256*3 floats
    if (t < 128) {
      const float* q = ep.aux0 + (long)bz * ep.saux + (long)(rbase + t) * 3;
      qs[t * 3] = q[0]; qs[t * 3 + 1] = q[1]; qs[t * 3 + 2] = q[2];
    } else if (t < 384) {
      const int tt = t - 128;
      const float* k2 = ep.aux1 + (long)bz * ep.saux + (long)(cbase + tt) * 3;
      ks2[tt * 3] = k2[0]; ks2[tt * 3 + 1] = k2[1]; ks2[tt * 3 + 2] = k2[2];
    }
    __syncthreads();
    unsigned short* C = (unsigned short*)Cout + (long)bz * sC;
    float* lrow = (float*)ep.aux2 + (long)bz * 2048 + rbase;
    float ps[4][4];
#pragma unroll
    for (int m = 0; m < 4; ++m) {
#pragma unroll
      for (int i = 0; i < 4; ++i) {
        ps[m][i] = 0.f;
        const int rl = wr * 64 + m * 16 + tg * 4 + i;
        const float qx = qs[rl * 3], qy = qs[rl * 3 + 1], qz = qs[rl * 3 + 2];
#pragma unroll
        for (int n = 0; n < 4; ++n) {
          const int cl = wc * 64 + n * 16 + tr;
          const float dx = qx - ks2[cl * 3];
          const float dy = qy - ks2[cl * 3 + 1];
          const float dz = qz - ks2[cl * 3 + 2];
          const float d2 = dx * dx + dy * dy + dz * dz;
          const float d  = sqrtf(fmaxf(d2, 1e-12f));
          const float bias = fmaxf(-2.f * d, -18.420680743952367f);
          const float p = __expf(acc[m][n][i] * ep.scale + bias - 5.f);
          ps[m][i] += p;
          C[(long)(rbase + rl) * ldc + (cbase + cl)] = f2bf(p);
        }
      }
    }
#pragma unroll
    for (int off = 1; off <= 8; off <<= 1)
#pragma unroll
      for (int m = 0; m < 4; ++m)
#pragma unroll
        for (int i = 0; i < 4; ++i)
          ps[m][i] += __shfl_xor(ps[m][i], off, 64);
    if (tr == 0) {
#pragma unroll
      for (int m = 0; m < 4; ++m)
#pragma unroll
        for (int i = 0; i < 4; ++i)
          atomicAdd(&lrow[wr * 64 + m * 16 + tg * 4 + i], ps[m][i]);
    }
  }
}

// LayerNorm rows of 512 fp32; one wave per row
__global__ __launch_bounds__(256)
void ln_rows(const float* __restrict__ X, const float* __restrict__ g,
             const float* __restrict__ b, float* __restrict__ O)
{
  const int row  = blockIdx.x * 4 + (threadIdx.x >> 6);
  const int lane = threadIdx.x & 63;
  const float* xp = X + (long)row * 512;

  f32x4 v0 = *(const f32x4*)(xp + lane * 4);
  f32x4 v1 = *(const f32x4*)(xp + 256 + lane * 4);

  float s = 0.f;
#pragma unroll
  for (int j = 0; j < 4; ++j) s += v0[j] + v1[j];
#pragma unroll
  for (int off = 32; off; off >>= 1) s += __shfl_xor(s, off, 64);
  const float mu = s * (1.f / 512.f);

  float vs = 0.f;
#pragma unroll
  for (int j = 0; j < 4; ++j) {
    float d0 = v0[j] - mu, d1 = v1[j] - mu;
    vs += d0 * d0 + d1 * d1;
  }
#pragma unroll
  for (int off = 32; off; off >>= 1) vs += __shfl_xor(vs, off, 64);
  const float r = rsqrtf(vs * (1.f / 512.f) + 1e-5f);

  f32x4 g0 = *(const f32x4*)(g + lane * 4);
  f32x4 g1 = *(const f32x4*)(g + 256 + lane * 4);
  f32x4 b0 = *(const f32x4*)(b + lane * 4);
  f32x4 b1 = *(const f32x4*)(b + 256 + lane * 4);

  f32x4 o0, o1;
#pragma unroll
  for (int j = 0; j < 4; ++j) {
    o0[j] = (v0[j] - mu) * r * g0[j] + b0[j];
    o1[j] = (v1[j] - mu) * r * g1[j] + b1[j];
  }
  float* op = O + (long)row * 512;
  *(f32x4*)(op + lane * 4) = o0;
  *(f32x4*)(op + 256 + lane * 4) = o1;
}

// fp32 -> bf16 for the two feature tensors (blockIdx.y selects)
__global__ __launch_bounds__(256)
void cvt_feat(const float* __restrict__ a, const float* __restrict__ b,
              unsigned short* __restrict__ oa, unsigned short* __restrict__ ob)
{
  const float* src = blockIdx.y ? b : a;
  unsigned short* dst = blockIdx.y ? ob : oa;
  const long i = blockIdx.x * 256 + threadIdx.x;
  const f32x4* s = (const f32x4*)src;
  f32x4 x = s[i * 2];
  f32x4 y = s[i * 2 + 1];
  us8 o;
#pragma unroll
  for (int j = 0; j < 4; ++j) { o[j] = f2bf(x[j]); o[4 + j] = f2bf(y[j]); }
  *(us8*)(dst + i * 8) = o;
}

// fp32 -> bf16 for the four weight matrices into one contiguous dst
__global__ __launch_bounds__(256)
void cvt_w(const float* __restrict__ w0, const float* __restrict__ w1,
           const float* __restrict__ w2, const float* __restrict__ w3,
           unsigned short* __restrict__ dst)
{
  const float* src = blockIdx.y == 0 ? w0 : blockIdx.y == 1 ? w1 : blockIdx.y == 2 ? w2 : w3;
  unsigned short* d = dst + (long)blockIdx.y * 262144;
  const long i = blockIdx.x * 256 + threadIdx.x;
  const f32x4* s = (const f32x4*)src;
  f32x4 x = s[i * 2];
  f32x4 y = s[i * 2 + 1];
  us8 o;
#pragma unroll
  for (int j = 0; j < 4; ++j) { o[j] = f2bf(x[j]); o[4 + j] = f2bf(y[j]); }
  *(us8*)(d + i * 8) = o;
}

extern "C" void kernel_launch(void* const* d_in, const int* in_sizes, int n_in,
                              void* d_out, int out_size, void* d_ws, size_t ws_size,
                              hipStream_t stream)
{
  const float* qxyz  = (const float*)d_in[0];
  const float* qfeat = (const float*)d_in[1];
  const float* kxyz  = (const float*)d_in[2];
  const float* kfeat = (const float*)d_in[3];
  const float* Wq = (const float*)d_in[4];
  const float* bq = (const float*)d_in[5];
  const float* Wk = (const float*)d_in[6];
  const float* bk = (const float*)d_in[7];
  const float* Wv = (const float*)d_in[8];
  const float* bv = (const float*)d_in[9];
  const float* Wo = (const float*)d_in[10];
  const float* bo = (const float*)d_in[11];
  const float* lng = (const float*)d_in[12];
  const float* lnb = (const float*)d_in[13];

  const long SZ_FEAT = 16777216;            // 8*2048*512*2
  char* ws = (char*)d_ws;
  if (ws_size < (size_t)153092096) return;  // need ~153 MB

  unsigned short* XQ  = (unsigned short*)(ws);
  unsigned short* XK  = (unsigned short*)(ws + SZ_FEAT);
  unsigned short* QB  = (unsigned short*)(ws + 2 * SZ_FEAT);
  unsigned short* KB  = (unsigned short*)(ws + 3 * SZ_FEAT);
  unsigned short* VT  = (unsigned short*)(ws + 4 * SZ_FEAT);
  unsigned short* WQB = (unsigned short*)(ws + 5 * SZ_FEAT);
  unsigned short* WKB = WQB + 262144;       // contiguous K|V weight block [1024][512]
  unsigned short* WOB = WQB + 786432;
  unsigned short* SB  = (unsigned short*)(ws + 5 * SZ_FEAT + 2097152);
  unsigned short* ATT = QB;                 // alias: Q dead after scores GEMM
  float* XRES = (float*)ws;                 // alias: XQ/XK dead after projections
  float* LSUM = (float*)(ws + SZ_FEAT);     // alias: XK dead after KV projection

  // 1. conversions (2 dispatches)
  cvt_feat<<<dim3(4096, 2), 256, 0, stream>>>(qfeat, kfeat, XQ, XK);
  cvt_w<<<dim3(128, 4), 256, 0, stream>>>(Wq, Wk, Wv, Wo, WQB);

  // 2. projections: Q, then combined K|V
  EpiParams e0{}; e0.bias = bq;
  gemm_bt<0><<<dim3(4, 128, 1), 256, 0, stream>>>(XQ, WQB, QB, 512, 512, 512, 512, 0, 0, 0, e0);
  EpiParams e1{}; e1.bias = bk; e1.aux1 = bv; e1.aux2 = VT;
  gemm_bt<4><<<dim3(8, 128, 1), 256, 0, stream>>>(XK, WKB, KB, 512, 512, 512, 512, 0, 0, 0, e1);

  // zero row-sum buffer (XK region now dead)
  hipMemsetAsync(LSUM, 0, 8 * 2048 * sizeof(float), stream);

  // 3. scores -> P = exp(s-5), row sums via atomics; 2-phase dbuf, batch->XCD pinned
  EpiParams es{}; es.aux0 = qxyz; es.aux1 = kxyz; es.aux2 = LSUM; es.saux = 2048 * 3;
  es.scale = 0.044194173824159216f;  // 1/sqrt(512)
  gemm2<2><<<dim3(8, 128), 512, 0, stream>>>(QB, KB, SB, 512, 512, 512, 2048,
                                             (long)2048 * 512, (long)2048 * 512,
                                             (long)2048 * 2048, 8, es);

  // 4. attended = (P @ V) / l : 2-phase dbuf, 256 blocks (full GPU)
  EpiParams ep{}; ep.aux2 = LSUM;
  gemm2<0><<<dim3(8, 32), 512, 0, stream>>>(SB, VT, ATT, 2048, 2048, 2048, 512,
                                            (long)2048 * 2048, (long)512 * 2048,
                                            (long)2048 * 512, 2, ep);

  // 5. out projection + bias + residual -> x (fp32)
  EpiParams eo{}; eo.bias = bo; eo.aux0 = qfeat;
  gemm_bt<3><<<dim3(4, 128, 1), 256, 0, stream>>>(ATT, WOB, XRES, 512, 512, 512, 512, 0, 0, 0, eo);

  // 6. LayerNorm -> out
  ln_rows<<<4096, 256, 0, stream>>>(XRES, lng, lnb, (float*)d_out);
}